// Round 7
// baseline (689.178 us; speedup 1.0000x reference)
//
#include <hip/hip_runtime.h>
#include <stdint.h>

#define NROWS 50000
#define KNB 16
#define DD 128
#define LN_EPS 1e-5f

typedef unsigned short ushort_t;

__device__ __forceinline__ float bf2f(uint32_t u) {
    union { uint32_t i; float f; } v; v.i = u << 16; return v.f;
}
__device__ __forceinline__ ushort_t f2bf(float f) {
    union { float f; uint32_t i; } v; v.f = f;
    uint32_t x = v.i;
    uint32_t r = x + 0x7fffu + ((x >> 16) & 1u);
    return (ushort_t)(r >> 16);
}
__device__ __forceinline__ uint32_t packbf(float a, float b) {
    return (uint32_t)f2bf(a) | ((uint32_t)f2bf(b) << 16);
}
__device__ __forceinline__ float leaky(float v) {
    return v > 0.0f ? v : 0.01f * v;
}

// out[r][j] = sum_d in[r][d] * W[j][d] + bias[j]   (fp32 in/bias/out; W -> LDS bf16)
__global__ __launch_bounds__(128) void linear_kernel(
    const float* __restrict__ in, const float* __restrict__ W,
    const float* __restrict__ bias, float* __restrict__ out,
    int nchunks)
{
    __shared__ ushort_t Wl[128 * 130];   // stride 130: 2-way bank aliasing only (free)
    const int tid = threadIdx.x;
    for (int i = tid; i < 128 * 64; i += 128) {
        int row = i >> 6;
        int cp  = (i & 63) << 1;
        float2 w = *(const float2*)(W + row * 128 + cp);
        *(uint32_t*)(&Wl[row * 130 + cp]) = packbf(w.x, w.y);
    }
    const int j = tid;
    const float bj = bias[j];
    __syncthreads();

    for (int c = blockIdx.x; c < nchunks; c += gridDim.x) {
        const int r0 = c << 2;   // 50000 = 4*12500, no tail
        float acc0 = bj, acc1 = bj, acc2 = bj, acc3 = bj;
        const float* ip = in + (size_t)r0 * DD;
        #pragma unroll 4
        for (int d = 0; d < DD; d += 4) {
            uint32_t wpa = *(const uint32_t*)(&Wl[j * 130 + d]);
            uint32_t wpb = *(const uint32_t*)(&Wl[j * 130 + d + 2]);
            float w0 = bf2f(wpa & 0xffffu), w1 = bf2f(wpa >> 16);
            float w2 = bf2f(wpb & 0xffffu), w3 = bf2f(wpb >> 16);
            float4 x0 = *(const float4*)(ip + 0 * DD + d);
            float4 x1 = *(const float4*)(ip + 1 * DD + d);
            float4 x2 = *(const float4*)(ip + 2 * DD + d);
            float4 x3 = *(const float4*)(ip + 3 * DD + d);
            acc0 += x0.x * w0 + x0.y * w1 + x0.z * w2 + x0.w * w3;
            acc1 += x1.x * w0 + x1.y * w1 + x1.z * w2 + x1.w * w3;
            acc2 += x2.x * w0 + x2.y * w1 + x2.z * w2 + x2.w * w3;
            acc3 += x3.x * w0 + x3.y * w1 + x3.z * w2 + x3.w * w3;
        }
        out[(size_t)(r0 + 0) * DD + j] = acc0;
        out[(size_t)(r0 + 1) * DD + j] = acc1;
        out[(size_t)(r0 + 2) * DD + j] = acc2;
        out[(size_t)(r0 + 3) * DD + j] = acc3;
    }
}

// Fused: attention (wave-per-row) -> a,m in LDS -> dual matvec W1/W2 -> LN -> fp32 out.
// e_h ALIASES out (e_h lives in d_out): row n's e_h is read in phase A and out[n]
// written in phase B of the same block-iteration, separated by __syncthreads;
// blocks own disjoint row sets -> safe.
__global__ __launch_bounds__(256) void mega_kernel(
    const float* e_h, const float* __restrict__ e_t,
    const int* __restrict__ topk_idx, const float* __restrict__ topk_w,
    const float* __restrict__ x,
    const float* __restrict__ W1, const float* __restrict__ b1,
    const float* __restrict__ W2, const float* __restrict__ b2,
    const float* __restrict__ gamma, const float* __restrict__ beta,
    float* out, int niters)
{
    __shared__ ushort_t W1l[128 * 130];
    __shared__ ushort_t W2l[128 * 130];
    __shared__ float aL[4 * 128];
    __shared__ float mL[4 * 128];
    __shared__ float red[16];

    const int tid  = threadIdx.x;
    const int wv   = tid >> 6;        // wave 0..3  (phase A: row wv)
    const int lane = tid & 63;
    const int half = tid >> 7;        // 0,1        (phase B: row pair)
    const int j    = tid & 127;       // column

    for (int i = tid; i < 128 * 64; i += 256) {
        int row = i >> 6;
        int cp  = (i & 63) << 1;
        float2 w1 = *(const float2*)(W1 + row * 128 + cp);
        float2 w2 = *(const float2*)(W2 + row * 128 + cp);
        *(uint32_t*)(&W1l[row * 130 + cp]) = packbf(w1.x, w1.y);
        *(uint32_t*)(&W2l[row * 130 + cp]) = packbf(w2.x, w2.y);
    }
    const float b1j = b1[j], b2j = b2[j];
    const float gj  = gamma[j], btj = beta[j];
    __syncthreads();

    for (int c = blockIdx.x; c < niters; c += gridDim.x) {
        const int r0 = c << 2;
        // ---- phase A: wave wv computes attention for row n = r0+wv ----
        {
            const int n = r0 + wv;
            const float2 ehv = *(const float2*)(e_h + (size_t)n * DD + 2 * lane);
            const float eh0 = ehv.x, eh1 = ehv.y;

            float nb0[KNB], nb1[KNB], s[KNB];
            const int* ipx = topk_idx + n * KNB;
            const float* wpx = topk_w + n * KNB;
            #pragma unroll
            for (int k = 0; k < KNB; ++k) {
                int t = ipx[k];
                t = ((unsigned)t < (unsigned)NROWS) ? t : 0;   // defensive clamp
                const float p = wpx[k];
                const float2 bv = *(const float2*)(e_t + (size_t)t * DD + 2 * lane);
                const float b0 = bv.x, b1v = bv.y;
                nb0[k] = b0; nb1[k] = b1v;
                const float er0 = p * b0  + (1.0f - p) * eh0;
                const float er1 = p * b1v + (1.0f - p) * eh1;
                const float g0 = tanhf(eh0 + er0);
                const float g1 = tanhf(eh1 + er1);
                float part = b0 * g0 + b1v * g1;
                #pragma unroll
                for (int off = 32; off >= 1; off >>= 1)
                    part += __shfl_xor(part, off, 64);
                s[k] = part;
            }
            float mx = s[0];
            #pragma unroll
            for (int k = 1; k < KNB; ++k) mx = fmaxf(mx, s[k]);
            float pr[KNB], sum = 0.0f;
            #pragma unroll
            for (int k = 0; k < KNB; ++k) { pr[k] = __expf(s[k] - mx); sum += pr[k]; }
            const float inv = 1.0f / sum;
            float e0 = 0.0f, e1 = 0.0f;
            #pragma unroll
            for (int k = 0; k < KNB; ++k) { e0 += pr[k] * nb0[k]; e1 += pr[k] * nb1[k]; }
            e0 *= inv; e1 *= inv;

            const float2 xv = *(const float2*)(x + (size_t)n * DD + 2 * lane);
            aL[wv * DD + 2 * lane]     = xv.x + e0;
            aL[wv * DD + 2 * lane + 1] = xv.y + e1;
            mL[wv * DD + 2 * lane]     = xv.x * e0;
            mL[wv * DD + 2 * lane + 1] = xv.y * e1;
        }
        __syncthreads();   // aL/mL ready; all e_h reads for rows r0..r0+3 complete

        // ---- phase B: thread (half, j): rows r0+2*half, r0+2*half+1, column j ----
        float aA0 = b1j, aA1 = b1j, aB0 = b2j, aB1 = b2j;
        const float* pa = &aL[(2 * half) * DD];
        const float* pm = &mL[(2 * half) * DD];
        #pragma unroll 8
        for (int d = 0; d < DD; d += 2) {
            uint32_t w1p = *(const uint32_t*)(&W1l[j * 130 + d]);
            uint32_t w2p = *(const uint32_t*)(&W2l[j * 130 + d]);
            float w10 = bf2f(w1p & 0xffffu), w11 = bf2f(w1p >> 16);
            float w20 = bf2f(w2p & 0xffffu), w21 = bf2f(w2p >> 16);
            float a00 = pa[d],      a01 = pa[d + 1];
            float a10 = pa[DD + d], a11 = pa[DD + d + 1];
            float m00 = pm[d],      m01 = pm[d + 1];
            float m10 = pm[DD + d], m11 = pm[DD + d + 1];
            aA0 += a00 * w10 + a01 * w11;
            aA1 += a10 * w10 + a11 * w11;
            aB0 += m00 * w20 + m01 * w21;
            aB1 += m10 * w20 + m11 * w21;
        }
        float h0 = leaky(aA0) + leaky(aB0);   // row r0+2*half
        float h1 = leaky(aA1) + leaky(aB1);   // row r0+2*half+1

        float s0 = h0, q0 = h0 * h0, s1 = h1, q1 = h1 * h1;
        #pragma unroll
        for (int off = 32; off >= 1; off >>= 1) {
            s0 += __shfl_xor(s0, off, 64);
            q0 += __shfl_xor(q0, off, 64);
            s1 += __shfl_xor(s1, off, 64);
            q1 += __shfl_xor(q1, off, 64);
        }
        if (lane == 0) {
            red[wv * 4 + 0] = s0; red[wv * 4 + 1] = q0;
            red[wv * 4 + 2] = s1; red[wv * 4 + 3] = q1;
        }
        __syncthreads();
        const int base = (wv & 2);   // waves {0,1} -> 0, waves {2,3} -> 2
        const float S0 = red[base * 4 + 0] + red[(base + 1) * 4 + 0];
        const float Q0 = red[base * 4 + 1] + red[(base + 1) * 4 + 1];
        const float S1 = red[base * 4 + 2] + red[(base + 1) * 4 + 2];
        const float Q1 = red[base * 4 + 3] + red[(base + 1) * 4 + 3];
        const float mu0 = S0 * (1.0f / DD);
        const float var0 = Q0 * (1.0f / DD) - mu0 * mu0;
        const float mu1 = S1 * (1.0f / DD);
        const float var1 = Q1 * (1.0f / DD) - mu1 * mu1;
        const int rA = r0 + 2 * half;
        out[(size_t)rA * DD + j]       = (h0 - mu0) * rsqrtf(var0 + LN_EPS) * gj + btj;
        out[(size_t)(rA + 1) * DD + j] = (h1 - mu1) * rsqrtf(var1 + LN_EPS) * gj + btj;
        __syncthreads();   // protect aL/mL/red before next iteration
    }
}

extern "C" void kernel_launch(void* const* d_in, const int* in_sizes, int n_in,
                              void* d_out, int out_size, void* d_ws, size_t ws_size,
                              hipStream_t stream) {
    const float* x      = (const float*)d_in[0];
    const float* ehi    = (const float*)d_in[1];
    const float* eti    = (const float*)d_in[2];
    const int*   tidx   = (const int*)d_in[3];
    const float* tw     = (const float*)d_in[4];
    const float* Wh     = (const float*)d_in[5];
    const float* bh     = (const float*)d_in[6];
    const float* Wt     = (const float*)d_in[7];
    const float* bt     = (const float*)d_in[8];
    const float* W1     = (const float*)d_in[9];
    const float* b1     = (const float*)d_in[10];
    const float* W2     = (const float*)d_in[11];
    const float* b2     = (const float*)d_in[12];
    const float* gamma  = (const float*)d_in[13];
    const float* beta   = (const float*)d_in[14];

    float* e_h = (float*)d_out;   // e_h staged in the fp32 output buffer (exact fit)
    float* e_t = (float*)d_ws;    // 25.6 MB of ws (<= 51.2 MB proven usable in R2)

    const int nchunks4 = NROWS / 4;   // 12500 exact

    linear_kernel<<<1024, 128, 0, stream>>>(ehi, Wh, bh, e_h, nchunks4);
    linear_kernel<<<1024, 128, 0, stream>>>(eti, Wt, bt, e_t, nchunks4);
    mega_kernel<<<1024, 256, 0, stream>>>(e_h, e_t, tidx, tw, x,
                                          W1, b1, W2, b2, gamma, beta,
                                          (float*)d_out, nchunks4);
}